// Round 8
// baseline (6616.052 us; speedup 1.0000x reference)
//
#include <hip/hip_runtime.h>
#include <hip/hip_bf16.h>
#include <stdint.h>

typedef __attribute__((ext_vector_type(8))) short   short8;
typedef __attribute__((ext_vector_type(8))) __bf16  bf16x8;
typedef __attribute__((ext_vector_type(4))) float   f32x4;

#define DEV __device__ __forceinline__

DEV float bf2f(uint16_t u){ union{uint32_t i; float f;} v; v.i = ((uint32_t)u)<<16; return v.f; }
DEV uint16_t f2bf(float f){ union{float f; uint32_t i;} v; v.f=f; uint32_t x=v.i;
  return (uint16_t)((x + 0x7fffu + ((x>>16)&1u))>>16); }
DEV float sigmf(float x){ return 1.0f/(1.0f + __expf(-x)); }
DEV float tanhx(float x){ x = fminf(15.f, fmaxf(-15.f, x)); float e = __expf(-2.0f*x);
  return (1.0f-e)/(1.0f+e); }

DEV bf16x8 as_bf(short8 s){ union{ short8 s; bf16x8 b; } u; u.s = s; return u.b; }
DEV f32x4 mfma16(short8 a, short8 b, f32x4 c){
  return __builtin_amdgcn_mfma_f32_16x16x32_bf16(as_bf(a), as_bf(b), c, 0, 0, 0);
}
DEV f32x4 vzero(){ f32x4 v; v[0]=0.f; v[1]=0.f; v[2]=0.f; v[3]=0.f; return v; }

// ---------------- small prep kernels ----------------
__global__ void cast_bf16_kernel(const float* __restrict__ in, uint16_t* __restrict__ out, int n){
  int i = blockIdx.x*256 + threadIdx.x;
  if (i < n) out[i] = f2bf(in[i]);
}

// rows of 128, store with XOR-swizzled 16B chunks (matches LDS strip layout)
__global__ void cast_swz_kernel(const float* __restrict__ in, uint16_t* __restrict__ out, int n){
  int i = blockIdx.x*256 + threadIdx.x;
  if (i < n){
    int k = i & 127, row = i >> 7;
    out[(row<<7) + (((k>>3) ^ (row&15))<<3) + (k&7)] = f2bf(in[i]);
  }
}

__global__ void xpad_kernel(const float* __restrict__ x, uint16_t* __restrict__ xb, int rows){
  int i = blockIdx.x*256 + threadIdx.x;
  if (i < rows*384){
    int r = i/384, c = i - r*384;
    xb[i] = (c < 369) ? f2bf(x[r*369 + c]) : (uint16_t)0;
  }
}

__global__ void lwt_kernel(const float* __restrict__ lw, uint16_t* __restrict__ lwT){
  int i = blockIdx.x*256 + threadIdx.x;   // out [128][384]: lwT[n][k] = lin_w[k][n]
  if (i < 128*384){
    int nn = i/384, k = i - nn*384;
    lwT[i] = (k < 369) ? f2bf(lw[k*128 + nn]) : (uint16_t)0;
  }
}

// ---------------- generic bf16 gemm: C[m][n] = sum_k A[m][k]*B[n][k] (+bias[n]) ----------------
__global__ __launch_bounds__(256,2)
void gemm_bt_kernel(const uint16_t* __restrict__ A, const uint16_t* __restrict__ B,
                    uint16_t* __restrict__ C,
                    int lda, int ldb, int M, int K4,
                    const float* __restrict__ bias, int swz,
                    long sA, long sB, long sC, int divA)
{
  int by = blockIdx.y;
  A += (long)(by/divA)*sA; B += (long)by*sB; C += (long)by*sC;
  int tid = threadIdx.x, lane = tid&63, wave = tid>>6;
  int l15 = lane&15, quad = lane>>4;
  int m0 = blockIdx.x*64 + wave*16;
  f32x4 acc[8];
  #pragma unroll
  for (int nf=0; nf<8; ++nf) acc[nf] = vzero();
  int mrow = min(m0 + l15, M-1);
  const char* arow = (const char*)(A + (long)mrow*lda) + quad*16;
  for (int kk=0; kk<K4; ++kk){
    short8 a = *(const short8*)(arow + kk*64);
    #pragma unroll
    for (int nf=0; nf<8; ++nf){
      const char* brow = (const char*)(B + (long)(nf*16+l15)*ldb) + quad*16;
      short8 b = *(const short8*)(brow + kk*64);
      acc[nf] = mfma16(a, b, acc[nf]);
    }
  }
  #pragma unroll
  for (int nf=0; nf<8; ++nf){
    int col = nf*16 + l15;
    float bb = bias ? bias[col] : 0.0f;
    #pragma unroll
    for (int i=0; i<4; ++i){
      int row = m0 + quad*4 + i;
      if (row < M){
        float v = acc[nf][i] + bb;
        int idx = swz ? (row*128 + (((col>>3)^(row&15))<<3) + (col&7)) : (row*128+col);
        C[idx] = f2bf(v);
      }
    }
  }
}

// ---------------- CSR build ----------------
__global__ void edge_count_kernel(const int* __restrict__ ei, const int* __restrict__ ea,
                                  int* __restrict__ cnt, int E, int n){
  int e = blockIdx.x*256 + threadIdx.x;
  if (e < E){
    int dst = ei[E + e];
    int t = ea[e];
    atomicAdd(&cnt[t*n + dst], 1);
  }
}

__global__ void csr_alloc_kernel(const int* __restrict__ cnt, int* __restrict__ row_start,
                                 int* __restrict__ cursor, int* __restrict__ total, int R){
  __shared__ int wsum[4];
  __shared__ int base;
  int i = blockIdx.x*256 + threadIdx.x;
  int c = (i < R) ? cnt[i] : 0;
  int lane = threadIdx.x & 63, wave = threadIdx.x >> 6;
  int x = c;
  #pragma unroll
  for (int d=1; d<64; d<<=1){ int y = __shfl_up(x, d, 64); if (lane >= d) x += y; }
  if (lane == 63) wsum[wave] = x;
  __syncthreads();
  if (threadIdx.x == 0){
    int s0=wsum[0], s1=wsum[1], s2=wsum[2], s3=wsum[3];
    base = atomicAdd(total, s0+s1+s2+s3);
    wsum[0]=0; wsum[1]=s0; wsum[2]=s0+s1; wsum[3]=s0+s1+s2;
  }
  __syncthreads();
  int st = base + wsum[wave] + (x - c);
  if (i < R){ row_start[i] = st; cursor[i] = st; }
}

__global__ void edge_fill_kernel(const int* __restrict__ ei, const int* __restrict__ ea,
                                 int* __restrict__ cursor, int* __restrict__ csr, int E, int n){
  int e = blockIdx.x*256 + threadIdx.x;
  if (e < E){
    int src = ei[e], dst = ei[E+e], t = ea[e];
    int pos = atomicAdd(&cursor[t*n + dst], 1);
    csr[pos] = src;
  }
}

// ---------------- Pass A: aggregation (pure gather, high occupancy) ----------------
// thread = (row, 8-col chunk); 16 threads cover a 128-col row (256B coalesced per edge)
__global__ void agg_kernel(const uint16_t* __restrict__ h_in_b,
                           uint16_t* __restrict__ agg_b,
                           const int* __restrict__ row_start_b,
                           const int* __restrict__ row_cnt_b,
                           const int* __restrict__ csr_src,
                           int n, int t_off, long hin_stride)
{
  const int t = t_off + blockIdx.y;
  const uint16_t* h_in = h_in_b + (long)blockIdx.y*hin_stride;
  uint16_t* agg = agg_b + (long)blockIdx.y*((long)n*128);
  int id = blockIdx.x*256 + threadIdx.x;
  int row = id >> 4, c = (id & 15) * 8;
  if (row < n){
    int st = row_start_b[(size_t)t*n + row];
    int cn = row_cnt_b  [(size_t)t*n + row];
    float acc[8] = {0,0,0,0,0,0,0,0};
    for (int e=0; e<cn; ++e){
      int src = csr_src[st + e];
      short8 v = *(const short8*)(h_in + (long)src*128 + c);
      #pragma unroll
      for (int j=0; j<8; ++j) acc[j] += bf2f((uint16_t)v[j]);
    }
    short8 pk;
    #pragma unroll
    for (int j=0; j<8; ++j) pk[j] = (short)f2bf(acc[j]);
    *(short8*)(agg + (long)row*128 + c) = pk;
  }
}

// ---------------- Pass B: dense GEMM + GRU, 128-row blocks, in-place h ----------------
// Block = 128 rows x 128 cols of one edge-type; 512 threads (8 waves, 16 rows/wave).
// 8 waves share each 32 KB weight staging -> LDS/barrier/weight-fetch per row halves.
// h update is in place for s>=1 (each block only touches its own rows).
__global__ __launch_bounds__(512, 4)
void ggnn_step_kernel(const uint16_t* __restrict__ h_in_b,
                      const uint16_t* __restrict__ agg_b,
                      uint16_t* __restrict__ h_out_b,
                      const uint16_t* __restrict__ W1_b,   // [T*8][384][128] swizzled
                      const uint16_t* __restrict__ W2_b,   // [T][384][128] swizzled
                      const float* __restrict__ bih_b,     // [T][384]
                      const float* __restrict__ bhh_b,     // [T][384]
                      int n, int s, int t_off,
                      long hin_stride, long hstride)
{
  __shared__ __align__(16) uint16_t sB[128*128];    // 32 KB
  const int t = t_off + blockIdx.y;
  const uint16_t* h_in = h_in_b + (long)blockIdx.y*hin_stride;
  const uint16_t* agg  = agg_b  + (long)blockIdx.y*hstride;
  uint16_t*       h_out= h_out_b+ (long)blockIdx.y*hstride;
  const uint16_t* W1s = W1_b + (size_t)(t*8+s)*384*128;
  const uint16_t* W2s = W2_b + (size_t)t*384*128;
  const float* bih = bih_b + t*384;
  const float* bhh = bhh_b + t*384;

  const int tid = threadIdx.x, lane = tid&63, wave = tid>>6;   // wave 0..7
  const int l15 = lane&15, quad = lane>>4;
  const int r0 = blockIdx.x*128 + wave*16;  // this wave's 16 rows
  const int ar = r0 + l15;                  // A-fragment row for this lane
  const int arc = min(ar, n-1);

  // strips in use order: rW1, rW2, nW1, nW2, zW1, zW2 (torch rows: r=0..127, z=128..255, n=256..383)
  const uint16_t* stp[6] = { W1s, W2s, W1s+2*16384, W2s+2*16384, W1s+16384, W2s+16384 };

  // ---- prefetch stage 0 weights into registers (512 thr x 16B x 4 = 32 KB) ----
  short8 tmp[4];
  {
    const char* g = (const char*)stp[0] + tid*16;
    #pragma unroll
    for (int it=0; it<4; ++it) tmp[it] = *(const short8*)(g + it*8192);
  }

  // ---- A-fragments: h (reused 3x) and agg (streamed dense) ----
  short8 hfr[4], afr[4];
  {
    const short8* hrow = (const short8*)(h_in + (long)arc*128);
    const short8* arow = (const short8*)(agg  + (long)arc*128);
    #pragma unroll
    for (int kk=0; kk<4; ++kk){ hfr[kk] = hrow[kk*4 + quad]; afr[kk] = arow[kk*4 + quad]; }
  }

  auto mma = [&](f32x4* a8, const short8* frag){
    #pragma unroll
    for (int kk=0; kk<4; ++kk){
      int ch = ((kk*4+quad)^l15)<<4;
      short8 a = frag[kk];
      #pragma unroll
      for (int nf=0; nf<8; ++nf){
        short8 b = *(const short8*)((const char*)sB + (nf*16+l15)*256 + ch);
        a8[nf] = mfma16(a, b, a8[nf]);
      }
    }
  };

  f32x4 rg[8], nng[8], zg[8];
  #pragma unroll
  for (int nf=0; nf<8; ++nf){ rg[nf]=vzero(); nng[nf]=vzero(); zg[nf]=vzero(); }

  // ---- 6 pipelined stages: store tmp->sB, prefetch next strip, mma ----
  #pragma unroll
  for (int g=0; g<6; ++g){
    __syncthreads();                       // prior mma on sB finished
    {
      char* l = (char*)sB + tid*16;
      #pragma unroll
      for (int it=0; it<4; ++it) *(short8*)(l + it*8192) = tmp[it];
    }
    __syncthreads();                       // sB ready
    if (g < 5){                            // prefetch next strip (overlaps mma+barrier)
      const char* gp = (const char*)stp[g+1] + tid*16;
      #pragma unroll
      for (int it=0; it<4; ++it) tmp[it] = *(const short8*)(gp + it*8192);
    }
    if (g == 0)      mma(rg, afr);
    else if (g == 1){
      mma(rg, hfr);
      #pragma unroll
      for (int nf=0; nf<8; ++nf){
        int col = nf*16 + l15;
        float bs = bih[col] + bhh[col];
        #pragma unroll
        for (int i=0; i<4; ++i) rg[nf][i] = sigmf(rg[nf][i] + bs);
      }
    }
    else if (g == 2) mma(nng, afr);
    else if (g == 3){
      f32x4 nh[8];
      #pragma unroll
      for (int nf=0; nf<8; ++nf) nh[nf] = vzero();
      mma(nh, hfr);
      #pragma unroll
      for (int nf=0; nf<8; ++nf){
        int col = nf*16 + l15;
        float bin = bih[256+col], bhn = bhh[256+col];
        #pragma unroll
        for (int i=0; i<4; ++i)
          nng[nf][i] = tanhx(nng[nf][i] + bin + rg[nf][i]*(nh[nf][i] + bhn));
      }
    }
    else if (g == 4) mma(zg, afr);
    else             mma(zg, hfr);
  }

  // ---- combine + direct C-layout writeout (in place: read-then-write same elem) ----
  #pragma unroll
  for (int nf=0; nf<8; ++nf){
    int col = nf*16 + l15;
    float bs = bih[128+col] + bhh[128+col];
    #pragma unroll
    for (int i=0; i<4; ++i){
      int row = r0 + quad*4 + i;
      if (row < n){
        float z = sigmf(zg[nf][i] + bs);
        float hv = bf2f(h_in[(long)row*128 + col]);
        float hnew = nng[nf][i] + z*(hv - nng[nf][i]);
        h_out[(long)row*128 + col] = f2bf(hnew);
      }
    }
  }
}

// ---------------- reduce final per-type h into messages ----------------
__global__ void reduce_kernel(const uint16_t* __restrict__ hfin, float* __restrict__ messages,
                              long stride, int nt, int accumulate, int total8){
  int i = blockIdx.x*256 + threadIdx.x;   // units of 8 elements
  if (i < total8){
    float acc[8];
    #pragma unroll
    for (int j=0;j<8;++j) acc[j] = 0.f;
    if (accumulate){
      #pragma unroll
      for (int j=0;j<8;++j) acc[j] = messages[(long)i*8 + j];
    }
    for (int t=0; t<nt; ++t){
      short8 v = *(const short8*)(hfin + (long)t*stride + (long)i*8);
      #pragma unroll
      for (int j=0;j<8;++j) acc[j] += bf2f((uint16_t)v[j]);
    }
    #pragma unroll
    for (int j=0;j<8;++j) messages[(long)i*8 + j] = acc[j];
  }
}

// ---------------- pooling + classifier ----------------
__global__ void pool_kernel(const float* __restrict__ messages, const int* __restrict__ batch,
                            float* __restrict__ sums, int* __restrict__ cntg, int n){
  int id = blockIdx.x*256 + threadIdx.x;
  int col = id & 127;
  int nb = (id >> 7) * 8;
  float acc = 0.f; int curg = -1; int ccount = 0;
  for (int j=0; j<8; ++j){
    int node = nb + j;
    if (node < n){
      int g = batch[node];
      if (g != curg){
        if (curg >= 0){
          atomicAdd(&sums[curg*128+col], acc);
          if (col == 0) atomicAdd(&cntg[curg], ccount);
        }
        curg = g; acc = 0.f; ccount = 0;
      }
      acc += messages[(long)node*128 + col];
      ccount++;
    }
  }
  if (curg >= 0){
    atomicAdd(&sums[curg*128+col], acc);
    if (col == 0) atomicAdd(&cntg[curg], ccount);
  }
}

__global__ void classify_kernel(const float* __restrict__ sums, const int* __restrict__ cntg,
                                const float* __restrict__ cls_w, const float* __restrict__ cls_b,
                                float* __restrict__ out, int G){
  int g = threadIdx.x;
  if (g < G){
    float inv = 1.0f / fmaxf((float)cntg[g], 1.0f);
    float o0 = 0.f, o1 = 0.f;
    for (int d=0; d<128; ++d){
      float p = sums[g*128+d]*inv;
      o0 += p*cls_w[d*2];
      o1 += p*cls_w[d*2+1];
    }
    out[g*2]   = o0 + cls_b[0];
    out[g*2+1] = o1 + cls_b[1];
  }
}

extern "C" void kernel_launch(void* const* d_in, const int* in_sizes, int n_in,
                              void* d_out, int out_size, void* d_ws, size_t ws_size,
                              hipStream_t stream)
{
  const float* x      = (const float*)d_in[0];
  const int*   ei     = (const int*)d_in[1];
  const int*   ea     = (const int*)d_in[2];
  const int*   batch  = (const int*)d_in[3];
  const float* lin_w  = (const float*)d_in[4];
  const float* lin_b  = (const float*)d_in[5];
  const float* ggnn_w = (const float*)d_in[6];
  const float* w_ih   = (const float*)d_in[7];
  const float* w_hh   = (const float*)d_in[8];
  const float* b_ih   = (const float*)d_in[9];
  const float* b_hh   = (const float*)d_in[10];
  const float* cls_w  = (const float*)d_in[11];
  const float* cls_b  = (const float*)d_in[12];
  float* out = (float*)d_out;

  const int N = in_sizes[3];          // 50000 nodes
  const int E = in_sizes[2];          // 800000 edges
  const int T = in_sizes[9] / 384;    // 13 edge types
  const int G = out_size / 2;         // 256 graphs
  const int STEPS = 8;

  // ---- workspace: persistent block + overlap region (prep buffers alias hT/agg) ----
  struct Layout {
    float *messages, *sums; int *cntg, *total;
    int *cnt, *row_start, *csr;
    uint16_t *W2t, *W1t, *h0;
    uint16_t *hT, *agg;
    int *cursor; uint16_t *xb, *lwT, *gwb, *wihb;
    size_t zero_off, zero_len, end;
  };
  auto make_layout = [&](int nh)->Layout{
    Layout L; char* base = (char*)d_ws; char* p = base;
    auto A = [&](size_t b)->char*{ char* r = p; p += (b + 255) & ~(size_t)255; return r; };
    L.messages  = (float*)A((size_t)N*128*4);
    char* z0 = p;
    L.sums      = (float*)A((size_t)G*128*4);
    L.cntg      = (int*)  A((size_t)G*4);
    L.total     = (int*)  A(256);
    L.zero_off = (size_t)(z0 - base); L.zero_len = (size_t)(p - z0);
    L.cnt       = (int*)  A((size_t)T*N*4);
    L.row_start = (int*)  A((size_t)T*N*4);
    L.csr       = (int*)  A((size_t)E*4);
    L.W2t       = (uint16_t*)A((size_t)T*384*128*2);
    L.W1t       = (uint16_t*)A((size_t)T*8*384*128*2);
    L.h0        = (uint16_t*)A((size_t)N*128*2);
    // overlap region: [hT | agg] || prep-only buffers
    char* R = p;
    size_t hb  = (size_t)N*128*2;
    size_t hba = ((size_t)nh*hb + 255) & ~(size_t)255;
    L.hT = (uint16_t*)R; L.agg = (uint16_t*)(R + hba);
    size_t hreg = 2*hba;
    char* q = R;
    auto B = [&](size_t b)->char*{ char* r = q; q += (b + 255) & ~(size_t)255; return r; };
    L.cursor = (int*)     B((size_t)T*N*4);
    L.xb     = (uint16_t*)B((size_t)N*384*2);
    L.lwT    = (uint16_t*)B((size_t)128*384*2);
    L.gwb    = (uint16_t*)B((size_t)T*8*128*128*2);
    L.wihb   = (uint16_t*)B((size_t)T*384*128*2);
    size_t preg = (size_t)(q - R);
    L.end = (size_t)(R - base) + (hreg > preg ? hreg : preg);
    return L;
  };
  // in-place h: working set 2*nh*12.8 MB; nh=7 -> ~179 MB + weights, L3-resident
  int nh = 1;
  { int cand[6] = {7, 6, 5, 4, 3, 2};
    for (int i=0; i<6; ++i){
      int c = cand[i] < T ? cand[i] : T;
      if (make_layout(c).end <= ws_size){ nh = c; break; }
    } }
  Layout L = make_layout(nh);

  hipMemsetAsync((char*)d_ws + L.zero_off, 0, L.zero_len, stream);   // sums/cntg/total
  hipMemsetAsync(L.cnt, 0, (size_t)T*N*4, stream);

  const int ngw = T*8*128*128, nwih = T*384*128;
  cast_bf16_kernel<<<(ngw+255)/256, 256, 0, stream>>>(ggnn_w, L.gwb, ngw);
  cast_bf16_kernel<<<(nwih+255)/256, 256, 0, stream>>>(w_ih, L.wihb, nwih);
  cast_swz_kernel <<<(nwih+255)/256, 256, 0, stream>>>(w_hh, L.W2t, nwih);
  xpad_kernel<<<((N*384)+255)/256, 256, 0, stream>>>(x, L.xb, N);
  lwt_kernel<<<(128*384+255)/256, 256, 0, stream>>>(lin_w, L.lwT);

  // W1t[t*8+s][j][k] = sum_d w_ih[t][j][d] * ggnn_w[t][s][k][d]  (swizzled store)
  gemm_bt_kernel<<<dim3(6, T*8), 256, 0, stream>>>(L.wihb, L.gwb, L.W1t, 128, 128, 384, 4,
      nullptr, 1, (long)384*128, (long)128*128, (long)384*128, 8);
  // h0 = xb @ lwT^T + lin_b   (plain store)
  gemm_bt_kernel<<<dim3((N+63)/64, 1), 256, 0, stream>>>(L.xb, L.lwT, L.h0, 384, 384, N, 12,
      lin_b, 0, 0, 0, 0, 1);

  edge_count_kernel<<<(E+255)/256, 256, 0, stream>>>(ei, ea, L.cnt, E, N);
  csr_alloc_kernel <<<(T*N+255)/256, 256, 0, stream>>>(L.cnt, L.row_start, L.cursor, L.total, T*N);
  edge_fill_kernel <<<(E+255)/256, 256, 0, stream>>>(ei, ea, L.cursor, L.csr, E, N);

  const int nblk = (N+127)/128;
  const int ablk = (N*16 + 255)/256;
  const long hs = (long)N*128;
  const int total8 = N*128/8;
  const int ngroups = (T + nh - 1)/nh;

  for (int gidx=0; gidx<ngroups; ++gidx){
    int t0 = gidx*nh, nt = (T - t0 < nh) ? (T - t0) : nh;
    for (int s=0; s<STEPS; ++s){
      const uint16_t* hin = (s==0) ? L.h0 : L.hT;
      long hin_stride = (s==0) ? 0 : hs;
      // Pass A: gather into agg (bandwidth-bound, high occupancy)
      agg_kernel<<<dim3(ablk, nt), 256, 0, stream>>>(
          hin, L.agg, L.row_start, L.cnt, L.csr, N, t0, hin_stride);
      // Pass B: dense dual-GEMM + GRU; writes hT (in place for s>=1)
      ggnn_step_kernel<<<dim3(nblk, nt), 512, 0, stream>>>(
          hin, L.agg, L.hT, L.W1t, L.W2t, b_ih, b_hh,
          N, s, t0, hin_stride, hs);
    }
    // fold this group's final h into messages
    reduce_kernel<<<(total8+255)/256, 256, 0, stream>>>(L.hT, L.messages, hs, nt,
                                                        (gidx>0) ? 1 : 0, total8);
  }

  pool_kernel<<<((N*128)+2047)/2048, 256, 0, stream>>>(L.messages, batch, L.sums, L.cntg, N);
  classify_kernel<<<1, 256, 0, stream>>>(L.sums, L.cntg, cls_w, cls_b, out, G);
}

// Round 9
// 3446.166 us; speedup vs baseline: 1.9198x; 1.9198x over previous
//
#include <hip/hip_runtime.h>
#include <hip/hip_bf16.h>
#include <stdint.h>

typedef __attribute__((ext_vector_type(8))) short   short8;
typedef __attribute__((ext_vector_type(8))) __bf16  bf16x8;
typedef __attribute__((ext_vector_type(4))) float   f32x4;

#define DEV __device__ __forceinline__

DEV float bf2f(uint16_t u){ union{uint32_t i; float f;} v; v.i = ((uint32_t)u)<<16; return v.f; }
DEV uint16_t f2bf(float f){
  union{ __hip_bfloat16 b; uint16_t u; } v; v.b = __float2bfloat16(f); return v.u;  // hw cvt, RNE
}
DEV float sigmf(float x){ return 1.0f/(1.0f + __expf(-x)); }
DEV float tanhx(float x){ x = fminf(15.f, fmaxf(-15.f, x)); float e = __expf(-2.0f*x);
  return (1.0f-e)/(1.0f+e); }

DEV bf16x8 as_bf(short8 s){ union{ short8 s; bf16x8 b; } u; u.s = s; return u.b; }
DEV f32x4 mfma16(short8 a, short8 b, f32x4 c){
  return __builtin_amdgcn_mfma_f32_16x16x32_bf16(as_bf(a), as_bf(b), c, 0, 0, 0);
}
DEV f32x4 vzero(){ f32x4 v; v[0]=0.f; v[1]=0.f; v[2]=0.f; v[3]=0.f; return v; }

// ---------------- small prep kernels ----------------
__global__ void cast_bf16_kernel(const float* __restrict__ in, uint16_t* __restrict__ out, int n){
  int i = blockIdx.x*256 + threadIdx.x;
  if (i < n) out[i] = f2bf(in[i]);
}

// rows of 128, store with XOR-swizzled 16B chunks (matches LDS strip layout)
__global__ void cast_swz_kernel(const float* __restrict__ in, uint16_t* __restrict__ out, int n){
  int i = blockIdx.x*256 + threadIdx.x;
  if (i < n){
    int k = i & 127, row = i >> 7;
    out[(row<<7) + (((k>>3) ^ (row&15))<<3) + (k&7)] = f2bf(in[i]);
  }
}

__global__ void xpad_kernel(const float* __restrict__ x, uint16_t* __restrict__ xb, int rows){
  int i = blockIdx.x*256 + threadIdx.x;
  if (i < rows*384){
    int r = i/384, c = i - r*384;
    xb[i] = (c < 369) ? f2bf(x[r*369 + c]) : (uint16_t)0;
  }
}

__global__ void lwt_kernel(const float* __restrict__ lw, uint16_t* __restrict__ lwT){
  int i = blockIdx.x*256 + threadIdx.x;   // out [128][384]: lwT[n][k] = lin_w[k][n]
  if (i < 128*384){
    int nn = i/384, k = i - nn*384;
    lwT[i] = (k < 369) ? f2bf(lw[k*128 + nn]) : (uint16_t)0;
  }
}

// ---------------- generic bf16 gemm: C[m][n] = sum_k A[m][k]*B[n][k] (+bias[n]) ----------------
__global__ __launch_bounds__(256,2)
void gemm_bt_kernel(const uint16_t* __restrict__ A, const uint16_t* __restrict__ B,
                    uint16_t* __restrict__ C,
                    int lda, int ldb, int M, int K4,
                    const float* __restrict__ bias, int swz,
                    long sA, long sB, long sC, int divA)
{
  int by = blockIdx.y;
  A += (long)(by/divA)*sA; B += (long)by*sB; C += (long)by*sC;
  int tid = threadIdx.x, lane = tid&63, wave = tid>>6;
  int l15 = lane&15, quad = lane>>4;
  int m0 = blockIdx.x*64 + wave*16;
  f32x4 acc[8];
  #pragma unroll
  for (int nf=0; nf<8; ++nf) acc[nf] = vzero();
  int mrow = min(m0 + l15, M-1);
  const char* arow = (const char*)(A + (long)mrow*lda) + quad*16;
  for (int kk=0; kk<K4; ++kk){
    short8 a = *(const short8*)(arow + kk*64);
    #pragma unroll
    for (int nf=0; nf<8; ++nf){
      const char* brow = (const char*)(B + (long)(nf*16+l15)*ldb) + quad*16;
      short8 b = *(const short8*)(brow + kk*64);
      acc[nf] = mfma16(a, b, acc[nf]);
    }
  }
  #pragma unroll
  for (int nf=0; nf<8; ++nf){
    int col = nf*16 + l15;
    float bb = bias ? bias[col] : 0.0f;
    #pragma unroll
    for (int i=0; i<4; ++i){
      int row = m0 + quad*4 + i;
      if (row < M){
        float v = acc[nf][i] + bb;
        int idx = swz ? (row*128 + (((col>>3)^(row&15))<<3) + (col&7)) : (row*128+col);
        C[idx] = f2bf(v);
      }
    }
  }
}

// ---------------- CSR build ----------------
__global__ void edge_count_kernel(const int* __restrict__ ei, const int* __restrict__ ea,
                                  int* __restrict__ cnt, int E, int n){
  int e = blockIdx.x*256 + threadIdx.x;
  if (e < E){
    int dst = ei[E + e];
    int t = ea[e];
    atomicAdd(&cnt[t*n + dst], 1);
  }
}

__global__ void csr_alloc_kernel(const int* __restrict__ cnt, int* __restrict__ row_start,
                                 int* __restrict__ cursor, int* __restrict__ total, int R){
  __shared__ int wsum[4];
  __shared__ int base;
  int i = blockIdx.x*256 + threadIdx.x;
  int c = (i < R) ? cnt[i] : 0;
  int lane = threadIdx.x & 63, wave = threadIdx.x >> 6;
  int x = c;
  #pragma unroll
  for (int d=1; d<64; d<<=1){ int y = __shfl_up(x, d, 64); if (lane >= d) x += y; }
  if (lane == 63) wsum[wave] = x;
  __syncthreads();
  if (threadIdx.x == 0){
    int s0=wsum[0], s1=wsum[1], s2=wsum[2], s3=wsum[3];
    base = atomicAdd(total, s0+s1+s2+s3);
    wsum[0]=0; wsum[1]=s0; wsum[2]=s0+s1; wsum[3]=s0+s1+s2;
  }
  __syncthreads();
  int st = base + wsum[wave] + (x - c);
  if (i < R){ row_start[i] = st; cursor[i] = st; }
}

__global__ void edge_fill_kernel(const int* __restrict__ ei, const int* __restrict__ ea,
                                 int* __restrict__ cursor, int* __restrict__ csr, int E, int n){
  int e = blockIdx.x*256 + threadIdx.x;
  if (e < E){
    int src = ei[e], dst = ei[E+e], t = ea[e];
    int pos = atomicAdd(&cursor[t*n + dst], 1);
    csr[pos] = src;
  }
}

// ---------------- Pass A: aggregation (pure gather, high occupancy) ----------------
// thread = (row, 8-col chunk); 16 threads cover a 128-col row (256B coalesced per edge)
__global__ void agg_kernel(const uint16_t* __restrict__ h_in_b,
                           uint16_t* __restrict__ agg_b,
                           const int* __restrict__ row_start_b,
                           const int* __restrict__ row_cnt_b,
                           const int* __restrict__ csr_src,
                           int n, int t_off, long hin_stride)
{
  const int t = t_off + blockIdx.y;
  const uint16_t* h_in = h_in_b + (long)blockIdx.y*hin_stride;
  uint16_t* agg = agg_b + (long)blockIdx.y*((long)n*128);
  int id = blockIdx.x*256 + threadIdx.x;
  int row = id >> 4, c = (id & 15) * 8;
  if (row < n){
    int st = row_start_b[(size_t)t*n + row];
    int cn = row_cnt_b  [(size_t)t*n + row];
    float acc[8] = {0,0,0,0,0,0,0,0};
    for (int e=0; e<cn; ++e){
      int src = csr_src[st + e];
      short8 v = *(const short8*)(h_in + (long)src*128 + c);
      #pragma unroll
      for (int j=0; j<8; ++j) acc[j] += bf2f((uint16_t)v[j]);
    }
    short8 pk;
    #pragma unroll
    for (int j=0; j<8; ++j) pk[j] = (short)f2bf(acc[j]);
    *(short8*)(agg + (long)row*128 + c) = pk;
  }
}

// ---------------- Pass B: dense GEMM + GRU (R7 structure, in-place h) ----------------
// Block = 64 rows x 128 cols of one edge-type; 256 threads; measured 128 VGPR, no spill.
// Touches only its own rows -> safe with h_in == h_out for s>=1.
__global__ __launch_bounds__(256, 2)
void ggnn_step_kernel(const uint16_t* __restrict__ h_in_b,
                      const uint16_t* __restrict__ agg_b,
                      uint16_t* __restrict__ h_out_b,
                      const uint16_t* __restrict__ W1_b,   // [T*8][384][128] swizzled
                      const uint16_t* __restrict__ W2_b,   // [T][384][128] swizzled
                      const float* __restrict__ bih_b,     // [T][384]
                      const float* __restrict__ bhh_b,     // [T][384]
                      int n, int s, int t_off,
                      long hin_stride, long hstride)
{
  __shared__ __align__(16) uint16_t sB[128*128];    // 32 KB
  const int t = t_off + blockIdx.y;
  const uint16_t* h_in = h_in_b + (long)blockIdx.y*hin_stride;
  const uint16_t* agg  = agg_b  + (long)blockIdx.y*hstride;
  uint16_t*       h_out= h_out_b+ (long)blockIdx.y*hstride;
  const uint16_t* W1s = W1_b + (size_t)(t*8+s)*384*128;
  const uint16_t* W2s = W2_b + (size_t)t*384*128;
  const float* bih = bih_b + t*384;
  const float* bhh = bhh_b + t*384;

  const int tid = threadIdx.x, lane = tid&63, wave = tid>>6;
  const int l15 = lane&15, quad = lane>>4;
  const int rbase = blockIdx.x*64;
  const int ar = rbase + wave*16 + l15;     // A-fragment row for this lane
  const int arc = min(ar, n-1);

  // strips in use order: rW1, rW2, nW1, nW2, zW1, zW2 (torch rows: r=0..127, z=128..255, n=256..383)
  const uint16_t* stp[6] = { W1s, W2s, W1s+2*16384, W2s+2*16384, W1s+16384, W2s+16384 };

  // ---- prefetch stage 0 weights into registers ----
  short8 tmp[8];
  {
    const char* g = (const char*)stp[0] + tid*16;
    #pragma unroll
    for (int it=0; it<8; ++it) tmp[it] = *(const short8*)(g + it*4096);
  }

  // ---- A-fragments: h (reused 3x) and agg (streamed dense) ----
  short8 hfr[4], afr[4];
  {
    const short8* hrow = (const short8*)(h_in + (long)arc*128);
    const short8* arow = (const short8*)(agg  + (long)arc*128);
    #pragma unroll
    for (int kk=0; kk<4; ++kk){ hfr[kk] = hrow[kk*4 + quad]; afr[kk] = arow[kk*4 + quad]; }
  }

  auto mma = [&](f32x4* a8, const short8* frag){
    #pragma unroll
    for (int kk=0; kk<4; ++kk){
      int ch = ((kk*4+quad)^l15)<<4;
      short8 a = frag[kk];
      #pragma unroll
      for (int nf=0; nf<8; ++nf){
        short8 b = *(const short8*)((const char*)sB + (nf*16+l15)*256 + ch);
        a8[nf] = mfma16(a, b, a8[nf]);
      }
    }
  };

  f32x4 rg[8], nng[8], zg[8];
  #pragma unroll
  for (int nf=0; nf<8; ++nf){ rg[nf]=vzero(); nng[nf]=vzero(); zg[nf]=vzero(); }

  // ---- 6 pipelined stages: store tmp->sB, prefetch next strip, mma ----
  #pragma unroll
  for (int g=0; g<6; ++g){
    __syncthreads();                       // prior mma on sB finished
    {
      char* l = (char*)sB + tid*16;
      #pragma unroll
      for (int it=0; it<8; ++it) *(short8*)(l + it*4096) = tmp[it];
    }
    __syncthreads();                       // sB ready
    if (g < 5){                            // prefetch next strip (overlaps mma+barrier)
      const char* gp = (const char*)stp[g+1] + tid*16;
      #pragma unroll
      for (int it=0; it<8; ++it) tmp[it] = *(const short8*)(gp + it*4096);
    }
    if (g == 0)      mma(rg, afr);
    else if (g == 1){
      mma(rg, hfr);
      #pragma unroll
      for (int nf=0; nf<8; ++nf){
        int col = nf*16 + l15;
        float bs = bih[col] + bhh[col];
        #pragma unroll
        for (int i=0; i<4; ++i) rg[nf][i] = sigmf(rg[nf][i] + bs);
      }
    }
    else if (g == 2) mma(nng, afr);
    else if (g == 3){
      f32x4 nh[8];
      #pragma unroll
      for (int nf=0; nf<8; ++nf) nh[nf] = vzero();
      mma(nh, hfr);
      #pragma unroll
      for (int nf=0; nf<8; ++nf){
        int col = nf*16 + l15;
        float bin = bih[256+col], bhn = bhh[256+col];
        #pragma unroll
        for (int i=0; i<4; ++i)
          nng[nf][i] = tanhx(nng[nf][i] + bin + rg[nf][i]*(nh[nf][i] + bhn));
      }
    }
    else if (g == 4) mma(zg, afr);
    else             mma(zg, hfr);
  }

  // ---- combine + direct C-layout writeout (in-place safe: own rows only) ----
  #pragma unroll
  for (int nf=0; nf<8; ++nf){
    int col = nf*16 + l15;
    float bs = bih[128+col] + bhh[128+col];
    #pragma unroll
    for (int i=0; i<4; ++i){
      int row = rbase + wave*16 + quad*4 + i;
      if (row < n){
        float z = sigmf(zg[nf][i] + bs);
        float hv = bf2f(h_in[(long)row*128 + col]);
        float hnew = nng[nf][i] + z*(hv - nng[nf][i]);
        h_out[(long)row*128 + col] = f2bf(hnew);
      }
    }
  }
}

// ---------------- reduce final per-type h into messages ----------------
__global__ void reduce_kernel(const uint16_t* __restrict__ hfin, float* __restrict__ messages,
                              long stride, int nt, int accumulate, int total8){
  int i = blockIdx.x*256 + threadIdx.x;   // units of 8 elements
  if (i < total8){
    float acc[8];
    #pragma unroll
    for (int j=0;j<8;++j) acc[j] = 0.f;
    if (accumulate){
      #pragma unroll
      for (int j=0;j<8;++j) acc[j] = messages[(long)i*8 + j];
    }
    for (int t=0; t<nt; ++t){
      short8 v = *(const short8*)(hfin + (long)t*stride + (long)i*8);
      #pragma unroll
      for (int j=0;j<8;++j) acc[j] += bf2f((uint16_t)v[j]);
    }
    #pragma unroll
    for (int j=0;j<8;++j) messages[(long)i*8 + j] = acc[j];
  }
}

// ---------------- pooling + classifier ----------------
__global__ void pool_kernel(const float* __restrict__ messages, const int* __restrict__ batch,
                            float* __restrict__ sums, int* __restrict__ cntg, int n){
  int id = blockIdx.x*256 + threadIdx.x;
  int col = id & 127;
  int nb = (id >> 7) * 8;
  float acc = 0.f; int curg = -1; int ccount = 0;
  for (int j=0; j<8; ++j){
    int node = nb + j;
    if (node < n){
      int g = batch[node];
      if (g != curg){
        if (curg >= 0){
          atomicAdd(&sums[curg*128+col], acc);
          if (col == 0) atomicAdd(&cntg[curg], ccount);
        }
        curg = g; acc = 0.f; ccount = 0;
      }
      acc += messages[(long)node*128 + col];
      ccount++;
    }
  }
  if (curg >= 0){
    atomicAdd(&sums[curg*128+col], acc);
    if (col == 0) atomicAdd(&cntg[curg], ccount);
  }
}

__global__ void classify_kernel(const float* __restrict__ sums, const int* __restrict__ cntg,
                                const float* __restrict__ cls_w, const float* __restrict__ cls_b,
                                float* __restrict__ out, int G){
  int g = threadIdx.x;
  if (g < G){
    float inv = 1.0f / fmaxf((float)cntg[g], 1.0f);
    float o0 = 0.f, o1 = 0.f;
    for (int d=0; d<128; ++d){
      float p = sums[g*128+d]*inv;
      o0 += p*cls_w[d*2];
      o1 += p*cls_w[d*2+1];
    }
    out[g*2]   = o0 + cls_b[0];
    out[g*2+1] = o1 + cls_b[1];
  }
}

extern "C" void kernel_launch(void* const* d_in, const int* in_sizes, int n_in,
                              void* d_out, int out_size, void* d_ws, size_t ws_size,
                              hipStream_t stream)
{
  const float* x      = (const float*)d_in[0];
  const int*   ei     = (const int*)d_in[1];
  const int*   ea     = (const int*)d_in[2];
  const int*   batch  = (const int*)d_in[3];
  const float* lin_w  = (const float*)d_in[4];
  const float* lin_b  = (const float*)d_in[5];
  const float* ggnn_w = (const float*)d_in[6];
  const float* w_ih   = (const float*)d_in[7];
  const float* w_hh   = (const float*)d_in[8];
  const float* b_ih   = (const float*)d_in[9];
  const float* b_hh   = (const float*)d_in[10];
  const float* cls_w  = (const float*)d_in[11];
  const float* cls_b  = (const float*)d_in[12];
  float* out = (float*)d_out;

  const int N = in_sizes[3];          // 50000 nodes
  const int E = in_sizes[2];          // 800000 edges
  const int T = in_sizes[9] / 384;    // 13 edge types
  const int G = out_size / 2;         // 256 graphs
  const int STEPS = 8;

  // ---- workspace: persistent block + overlap region (prep buffers alias hT/agg) ----
  struct Layout {
    float *messages, *sums; int *cntg, *total;
    int *cnt, *row_start, *csr;
    uint16_t *W2t, *W1t, *h0;
    uint16_t *hT, *agg;
    int *cursor; uint16_t *xb, *lwT, *gwb, *wihb;
    size_t zero_off, zero_len, end;
  };
  auto make_layout = [&](int nh)->Layout{
    Layout L; char* base = (char*)d_ws; char* p = base;
    auto A = [&](size_t b)->char*{ char* r = p; p += (b + 255) & ~(size_t)255; return r; };
    L.messages  = (float*)A((size_t)N*128*4);
    char* z0 = p;
    L.sums      = (float*)A((size_t)G*128*4);
    L.cntg      = (int*)  A((size_t)G*4);
    L.total     = (int*)  A(256);
    L.zero_off = (size_t)(z0 - base); L.zero_len = (size_t)(p - z0);
    L.cnt       = (int*)  A((size_t)T*N*4);
    L.row_start = (int*)  A((size_t)T*N*4);
    L.csr       = (int*)  A((size_t)E*4);
    L.W2t       = (uint16_t*)A((size_t)T*384*128*2);
    L.W1t       = (uint16_t*)A((size_t)T*8*384*128*2);
    L.h0        = (uint16_t*)A((size_t)N*128*2);
    // overlap region: [hT | agg] || prep-only buffers
    char* R = p;
    size_t hb  = (size_t)N*128*2;
    size_t hba = ((size_t)nh*hb + 255) & ~(size_t)255;
    L.hT = (uint16_t*)R; L.agg = (uint16_t*)(R + hba);
    size_t hreg = 2*hba;
    char* q = R;
    auto B = [&](size_t b)->char*{ char* r = q; q += (b + 255) & ~(size_t)255; return r; };
    L.cursor = (int*)     B((size_t)T*N*4);
    L.xb     = (uint16_t*)B((size_t)N*384*2);
    L.lwT    = (uint16_t*)B((size_t)128*384*2);
    L.gwb    = (uint16_t*)B((size_t)T*8*128*128*2);
    L.wihb   = (uint16_t*)B((size_t)T*384*128*2);
    size_t preg = (size_t)(q - R);
    L.end = (size_t)(R - base) + (hreg > preg ? hreg : preg);
    return L;
  };
  // in-place h: working set 2*nh*12.8 MB; nh=7 -> ~179 MB + weights, L3-resident
  int nh = 1;
  { int cand[6] = {7, 6, 5, 4, 3, 2};
    for (int i=0; i<6; ++i){
      int c = cand[i] < T ? cand[i] : T;
      if (make_layout(c).end <= ws_size){ nh = c; break; }
    } }
  Layout L = make_layout(nh);

  hipMemsetAsync((char*)d_ws + L.zero_off, 0, L.zero_len, stream);   // sums/cntg/total
  hipMemsetAsync(L.cnt, 0, (size_t)T*N*4, stream);

  const int ngw = T*8*128*128, nwih = T*384*128;
  cast_bf16_kernel<<<(ngw+255)/256, 256, 0, stream>>>(ggnn_w, L.gwb, ngw);
  cast_bf16_kernel<<<(nwih+255)/256, 256, 0, stream>>>(w_ih, L.wihb, nwih);
  cast_swz_kernel <<<(nwih+255)/256, 256, 0, stream>>>(w_hh, L.W2t, nwih);
  xpad_kernel<<<((N*384)+255)/256, 256, 0, stream>>>(x, L.xb, N);
  lwt_kernel<<<(128*384+255)/256, 256, 0, stream>>>(lin_w, L.lwT);

  // W1t[t*8+s][j][k] = sum_d w_ih[t][j][d] * ggnn_w[t][s][k][d]  (swizzled store)
  gemm_bt_kernel<<<dim3(6, T*8), 256, 0, stream>>>(L.wihb, L.gwb, L.W1t, 128, 128, 384, 4,
      nullptr, 1, (long)384*128, (long)128*128, (long)384*128, 8);
  // h0 = xb @ lwT^T + lin_b   (plain store)
  gemm_bt_kernel<<<dim3((N+63)/64, 1), 256, 0, stream>>>(L.xb, L.lwT, L.h0, 384, 384, N, 12,
      lin_b, 0, 0, 0, 0, 1);

  edge_count_kernel<<<(E+255)/256, 256, 0, stream>>>(ei, ea, L.cnt, E, N);
  csr_alloc_kernel <<<(T*N+255)/256, 256, 0, stream>>>(L.cnt, L.row_start, L.cursor, L.total, T*N);
  edge_fill_kernel <<<(E+255)/256, 256, 0, stream>>>(ei, ea, L.cursor, L.csr, E, N);

  const int nblk = (N+63)/64;
  const int ablk = (N*16 + 255)/256;
  const long hs = (long)N*128;
  const int total8 = N*128/8;
  const int ngroups = (T + nh - 1)/nh;

  for (int gidx=0; gidx<ngroups; ++gidx){
    int t0 = gidx*nh, nt = (T - t0 < nh) ? (T - t0) : nh;
    for (int s=0; s<STEPS; ++s){
      const uint16_t* hin = (s==0) ? L.h0 : L.hT;
      long hin_stride = (s==0) ? 0 : hs;
      // Pass A: gather into agg (bandwidth-bound, high occupancy)
      agg_kernel<<<dim3(ablk, nt), 256, 0, stream>>>(
          hin, L.agg, L.row_start, L.cnt, L.csr, N, t0, hin_stride);
      // Pass B: dense dual-GEMM + GRU; writes hT (in place for s>=1)
      ggnn_step_kernel<<<dim3(nblk, nt), 256, 0, stream>>>(
          hin, L.agg, L.hT, L.W1t, L.W2t, b_ih, b_hh,
          N, s, t0, hin_stride, hs);
    }
    // fold this group's final h into messages
    reduce_kernel<<<(total8+255)/256, 256, 0, stream>>>(L.hT, L.messages, hs, nt,
                                                        (gidx>0) ? 1 : 0, total8);
  }

  pool_kernel<<<((N*128)+2047)/2048, 256, 0, stream>>>(L.messages, batch, L.sums, L.cntg, N);
  classify_kernel<<<1, 256, 0, stream>>>(L.sums, L.cntg, cls_w, cls_b, out, G);
}